// Round 1
// baseline (1897.440 us; speedup 1.0000x reference)
//
#include <hip/hip_runtime.h>
#include <math.h>

#define FIN 512
#define H   64
#define C   20

// ---------------- edge-index layout detection ----------------
// If edge_index was delivered as raw int64 (little-endian), every odd 32-bit
// word of the first entries is the high word of a value < 2^31 -> 0.
// If delivered as int32, odd words are genuine indices (~never all zero).
__global__ void detect_kernel(const int* __restrict__ ei, int n_check, int* flag) {
    __shared__ int nz;
    if (threadIdx.x == 0) nz = 0;
    __syncthreads();
    for (int i = threadIdx.x; i < n_check; i += blockDim.x)
        if (ei[2 * i + 1] != 0) nz = 1;   // benign race
    __syncthreads();
    if (threadIdx.x == 0) *flag = (nz == 0) ? 1 : 0;   // 1 => int64 layout
}

__device__ __forceinline__ int edge_val(const int* __restrict__ ei, long long idx, int m64) {
    return m64 ? ei[2 * idx] : ei[(int)idx];
}

// ---------------- degree (weighted, edges only; +1 self-loop added later) ----
__global__ void deg_kernel(const int* __restrict__ ei, const float* __restrict__ ew,
                           float* __restrict__ deg, int E, const int* __restrict__ flag) {
    int m64 = *flag;
    int e = blockIdx.x * blockDim.x + threadIdx.x;
    if (e < E) {
        int d = edge_val(ei, (long long)E + e, m64);
        atomicAdd(&deg[d], ew[e]);
    }
}

// dinv = rsqrt(deg + 1)   (self-loop weight 1 => deg always > 0)
__global__ void dinv_kernel(float* __restrict__ deg, int N) {
    int i = blockIdx.x * blockDim.x + threadIdx.x;
    if (i < N) deg[i] = rsqrtf(deg[i] + 1.0f);
}

// ---------------- GEMM1: xw1[N,64] = x[N,512] @ W1[512,64] -------------------
#define G1_ROWS 16
__global__ void gemm1_kernel(const float* __restrict__ x, const float* __restrict__ W,
                             float* __restrict__ xw, int N) {
    __shared__ float xs[G1_ROWS][FIN + 1];   // +1 pad: rows land on distinct banks
    int row0 = blockIdx.x * G1_ROWS;         // N % 16 == 0 for N=100000
    for (int t = threadIdx.x; t < G1_ROWS * FIN; t += 256) {
        int r = t >> 9, k = t & 511;
        xs[r][k] = x[(long long)(row0 + r) * FIN + k];
    }
    __syncthreads();
    int colg = threadIdx.x & 15;   // 16 col-groups of 4
    int row  = threadIdx.x >> 4;   // 16 rows
    int col0 = colg * 4;
    float a0 = 0.f, a1 = 0.f, a2 = 0.f, a3 = 0.f;
    #pragma unroll 8
    for (int k = 0; k < FIN; k++) {
        float xv = xs[row][k];
        float4 w = *(const float4*)&W[k * H + col0];
        a0 = fmaf(xv, w.x, a0);
        a1 = fmaf(xv, w.y, a1);
        a2 = fmaf(xv, w.z, a2);
        a3 = fmaf(xv, w.w, a3);
    }
    float4 r4 = make_float4(a0, a1, a2, a3);
    *(float4*)&xw[(long long)(row0 + row) * H + col0] = r4;
}

// ---------------- scatter layer 1: h1[dst] += xw1[src] * norm ----------------
__global__ void scatter1_kernel(const int* __restrict__ ei, const float* __restrict__ ew,
                                const float* __restrict__ dinv, const float* __restrict__ xw,
                                float* __restrict__ h1, int E, const int* __restrict__ flag) {
    int m64 = *flag;
    long long gid = (long long)blockIdx.x * blockDim.x + threadIdx.x;
    int lane = (int)(gid & 63);
    long long e = gid >> 6;
    if (e >= E) return;
    int s = edge_val(ei, e, m64);
    int d = edge_val(ei, (long long)E + e, m64);
    float norm = dinv[s] * ew[e] * dinv[d];
    float v = xw[(long long)s * H + lane] * norm;
    atomicAdd(&h1[(long long)d * H + lane], v);
}

// self-loop + bias + relu for layer 1
__global__ void self1_kernel(const float* __restrict__ xw, const float* __restrict__ dinv,
                             const float* __restrict__ b, float* __restrict__ h1, int N) {
    long long gid = (long long)blockIdx.x * blockDim.x + threadIdx.x;
    if (gid >= (long long)N * H) return;
    int i = (int)(gid >> 6);
    int c = (int)(gid & 63);
    float di = dinv[i];
    float v = h1[gid] + xw[gid] * di * di + b[c];
    h1[gid] = fmaxf(v, 0.f);
}

// ---------------- GEMM2: xw2[N,20] = h1[N,64] @ W2[64,20] --------------------
#define G2_ROWS 12
__global__ void gemm2_kernel(const float* __restrict__ h1, const float* __restrict__ W2,
                             float* __restrict__ xw2, int N) {
    __shared__ float hs[G2_ROWS][H + 1];
    __shared__ float ws2[H * C];
    int row0 = blockIdx.x * G2_ROWS;
    for (int t = threadIdx.x; t < H * C; t += 256) ws2[t] = W2[t];
    for (int t = threadIdx.x; t < G2_ROWS * H; t += 256) {
        int r = t >> 6, k = t & 63;
        int row = row0 + r;
        hs[r][k] = (row < N) ? h1[(long long)row * H + k] : 0.f;
    }
    __syncthreads();
    int t = threadIdx.x;
    if (t < G2_ROWS * C) {
        int r = t / C, c = t % C;
        int row = row0 + r;
        if (row < N) {
            float acc = 0.f;
            #pragma unroll
            for (int k = 0; k < H; k++) acc = fmaf(hs[r][k], ws2[k * C + c], acc);
            xw2[(long long)row * C + c] = acc;   // contiguous in t -> coalesced
        }
    }
}

// ---------------- scatter layer 2: h2[dst] += xw2[src] * norm ----------------
__global__ void scatter2_kernel(const int* __restrict__ ei, const float* __restrict__ ew,
                                const float* __restrict__ dinv, const float* __restrict__ xw2,
                                float* __restrict__ h2, int E, const int* __restrict__ flag) {
    int m64 = *flag;
    long long gid = (long long)blockIdx.x * blockDim.x + threadIdx.x;
    if (gid >= (long long)E * C) return;
    long long e = gid / C;
    int c = (int)(gid - e * C);
    int s = edge_val(ei, e, m64);
    int d = edge_val(ei, (long long)E + e, m64);
    float norm = dinv[s] * ew[e] * dinv[d];
    float v = xw2[(long long)s * C + c] * norm;
    atomicAdd(&h2[(long long)d * C + c], v);
}

// ---------------- final: self-loop + bias + softmax --------------------------
#define F_ROWS 12
__global__ void final_kernel(const float* __restrict__ xw2, const float* __restrict__ dinv,
                             const float* __restrict__ b2, const float* __restrict__ h2,
                             float* __restrict__ out, int N) {
    __shared__ float buf[F_ROWS][C];
    int row0 = blockIdx.x * F_ROWS;
    int t = threadIdx.x;
    if (t < F_ROWS * C) {
        int r = t / C, c = t - r * C;
        int row = row0 + r;
        if (row < N) {
            long long g = (long long)row0 * C + t;   // contiguous -> coalesced
            float di = dinv[row];
            buf[r][c] = h2[g] + xw2[g] * di * di + b2[c];
        }
    }
    __syncthreads();
    if (t < F_ROWS && (row0 + t) < N) {
        float mx = -1e30f;
        #pragma unroll
        for (int c = 0; c < C; c++) mx = fmaxf(mx, buf[t][c]);
        float s = 0.f;
        #pragma unroll
        for (int c = 0; c < C; c++) { float e = expf(buf[t][c] - mx); buf[t][c] = e; s += e; }
        float inv = 1.f / s;
        #pragma unroll
        for (int c = 0; c < C; c++) buf[t][c] *= inv;
    }
    __syncthreads();
    if (t < F_ROWS * C && (row0 * C + t) < (long long)N * C) {
        out[(long long)row0 * C + t] = buf[t / C][t % C];
    }
}

// ---------------- launch -----------------------------------------------------
static inline size_t align256(size_t x) { return (x + 255) & ~(size_t)255; }

extern "C" void kernel_launch(void* const* d_in, const int* in_sizes, int n_in,
                              void* d_out, int out_size, void* d_ws, size_t ws_size,
                              hipStream_t stream) {
    const float* x  = (const float*)d_in[0];
    const int*   ei = (const int*)d_in[1];
    const float* ew = (const float*)d_in[2];
    const float* W1 = (const float*)d_in[3];
    const float* b1 = (const float*)d_in[4];
    const float* W2 = (const float*)d_in[5];
    const float* b2 = (const float*)d_in[6];
    float* out = (float*)d_out;

    int N = in_sizes[0] / FIN;   // 100000
    int E = in_sizes[2];         // 3200000

    char* ws = (char*)d_ws;
    size_t off = 0;
    float* deg  = (float*)(ws + off); off = align256(off + (size_t)N * 4);
    int*   flag = (int*)(ws + off);   off = align256(off + 4);
    float* xw1  = (float*)(ws + off); off = align256(off + (size_t)N * H * 4);
    float* h1   = (float*)(ws + off); off = align256(off + (size_t)N * H * 4);
    float* xw2  = (float*)(ws + off); off = align256(off + (size_t)N * C * 4);
    float* h2   = (float*)(ws + off); off = align256(off + (size_t)N * C * 4);

    // zero accumulators (ws is poisoned to 0xAA before every timed call)
    hipMemsetAsync(deg, 0, (size_t)N * 4, stream);
    hipMemsetAsync(h1,  0, (size_t)N * H * 4, stream);
    hipMemsetAsync(h2,  0, (size_t)N * C * 4, stream);

    detect_kernel<<<1, 256, 0, stream>>>(ei, 256, flag);

    deg_kernel<<<(E + 255) / 256, 256, 0, stream>>>(ei, ew, deg, E, flag);
    dinv_kernel<<<(N + 255) / 256, 256, 0, stream>>>(deg, N);

    gemm1_kernel<<<N / G1_ROWS, 256, 0, stream>>>(x, W1, xw1, N);

    long long s1_threads = (long long)E * H;
    scatter1_kernel<<<(int)((s1_threads + 255) / 256), 256, 0, stream>>>(ei, ew, deg, xw1, h1, E, flag);
    self1_kernel<<<(int)(((long long)N * H + 255) / 256), 256, 0, stream>>>(xw1, deg, b1, h1, N);

    gemm2_kernel<<<(N + G2_ROWS - 1) / G2_ROWS, 256, 0, stream>>>(h1, W2, xw2, N);

    long long s2_threads = (long long)E * C;
    scatter2_kernel<<<(int)((s2_threads + 255) / 256), 256, 0, stream>>>(ei, ew, deg, xw2, h2, E, flag);

    final_kernel<<<(N + F_ROWS - 1) / F_ROWS, 256, 0, stream>>>(xw2, deg, b2, h2, out, N);
}

// Round 2
// 1431.548 us; speedup vs baseline: 1.3254x; 1.3254x over previous
//
#include <hip/hip_runtime.h>
#include <math.h>

#define FIN 512
#define H   64
#define C   20

// ---------------- edge-index layout detection ----------------
// int64 little-endian delivery => odd 32-bit words of first entries all zero.
__global__ void detect_kernel(const int* __restrict__ ei, int n_check, int* flag) {
    __shared__ int nz;
    if (threadIdx.x == 0) nz = 0;
    __syncthreads();
    for (int i = threadIdx.x; i < n_check; i += blockDim.x)
        if (ei[2 * i + 1] != 0) nz = 1;   // benign race
    __syncthreads();
    if (threadIdx.x == 0) *flag = (nz == 0) ? 1 : 0;   // 1 => int64 layout
}

__device__ __forceinline__ int edge_val(const int* __restrict__ ei, long long idx, int m64) {
    return m64 ? ei[2 * idx] : ei[(int)idx];
}

// ---------------- histogram: per-dst edge count + weighted degree ------------
__global__ void hist_kernel(const int* __restrict__ ei, const float* __restrict__ ew,
                            int* __restrict__ counts, float* __restrict__ deg,
                            int E, const int* __restrict__ flag) {
    int m64 = *flag;
    int e = blockIdx.x * blockDim.x + threadIdx.x;
    if (e < E) {
        int d = edge_val(ei, (long long)E + e, m64);
        atomicAdd(&counts[d], 1);
        atomicAdd(&deg[d], ew[e]);
    }
}

// dinv = rsqrt(deg + 1)   (self-loop weight 1 => deg always > 0)
__global__ void dinv_kernel(float* __restrict__ deg, int N) {
    int i = blockIdx.x * blockDim.x + threadIdx.x;
    if (i < N) deg[i] = rsqrtf(deg[i] + 1.0f);
}

// ---------------- CSR build: 3-kernel exclusive scan over counts -------------
// chunk = 1024 items per block (256 threads x 4)
__global__ void block_sums_kernel(const int* __restrict__ counts, int* __restrict__ bsum, int N) {
    __shared__ int lds[256];
    int t = threadIdx.x;
    int base = blockIdx.x * 1024 + t * 4;
    int s = 0;
    #pragma unroll
    for (int k = 0; k < 4; k++) { int i = base + k; if (i < N) s += counts[i]; }
    lds[t] = s; __syncthreads();
    for (int off = 128; off > 0; off >>= 1) {
        if (t < off) lds[t] += lds[t + off];
        __syncthreads();
    }
    if (t == 0) bsum[blockIdx.x] = lds[0];
}

__global__ void scan_bsums_kernel(int* __restrict__ bsum, int NB,
                                  int* __restrict__ rowptr, int N, int E) {
    __shared__ int lds[1024];
    int t = threadIdx.x;
    for (int i = t; i < NB; i += blockDim.x) lds[i] = bsum[i];
    __syncthreads();
    if (t == 0) {
        int run = 0;
        for (int i = 0; i < NB; i++) { int v = lds[i]; lds[i] = run; run += v; }
        rowptr[N] = E;
    }
    __syncthreads();
    for (int i = t; i < NB; i += blockDim.x) bsum[i] = lds[i];
}

__global__ void scan_local_kernel(const int* __restrict__ counts, const int* __restrict__ bsum,
                                  int* __restrict__ rowptr, int N) {
    __shared__ int lds[256];
    int t = threadIdx.x;
    int base = blockIdx.x * 1024 + t * 4;
    int c[4]; int s = 0;
    #pragma unroll
    for (int k = 0; k < 4; k++) { int i = base + k; c[k] = (i < N) ? counts[i] : 0; s += c[k]; }
    lds[t] = s; __syncthreads();
    for (int off = 1; off < 256; off <<= 1) {          // inclusive Hillis-Steele
        int add = (t >= off) ? lds[t - off] : 0;
        __syncthreads();
        lds[t] += add;
        __syncthreads();
    }
    int start = bsum[blockIdx.x] + lds[t] - s;          // exclusive prefix
    #pragma unroll
    for (int k = 0; k < 4; k++) {
        int i = base + k;
        if (i < N) { rowptr[i] = start; start += c[k]; }
    }
}

// fill: edata[pos] = {src, norm}  bucketed by dst via atomic cursor
__global__ void fill_kernel(const int* __restrict__ ei, const float* __restrict__ ew,
                            const float* __restrict__ dinv, int* __restrict__ cursor,
                            int2* __restrict__ edata, int E, const int* __restrict__ flag) {
    int m64 = *flag;
    int e = blockIdx.x * blockDim.x + threadIdx.x;
    if (e < E) {
        int s = edge_val(ei, e, m64);
        int d = edge_val(ei, (long long)E + e, m64);
        float norm = dinv[s] * ew[e] * dinv[d];
        int pos = atomicAdd(&cursor[d], 1);
        edata[pos] = make_int2(s, __float_as_int(norm));
    }
}

// ---------------- GEMM1: xw1[N,64] = x[N,512] @ W1[512,64] -------------------
#define G1_ROWS 16
__global__ void gemm1_kernel(const float* __restrict__ x, const float* __restrict__ W,
                             float* __restrict__ xw, int N) {
    __shared__ float xs[G1_ROWS][FIN + 1];
    int row0 = blockIdx.x * G1_ROWS;
    for (int t = threadIdx.x; t < G1_ROWS * FIN; t += 256) {
        int r = t >> 9, k = t & 511;
        xs[r][k] = x[(long long)(row0 + r) * FIN + k];
    }
    __syncthreads();
    int colg = threadIdx.x & 15;
    int row  = threadIdx.x >> 4;
    int col0 = colg * 4;
    float a0 = 0.f, a1 = 0.f, a2 = 0.f, a3 = 0.f;
    #pragma unroll 8
    for (int k = 0; k < FIN; k++) {
        float xv = xs[row][k];
        float4 w = *(const float4*)&W[k * H + col0];
        a0 = fmaf(xv, w.x, a0);
        a1 = fmaf(xv, w.y, a1);
        a2 = fmaf(xv, w.z, a2);
        a3 = fmaf(xv, w.w, a3);
    }
    *(float4*)&xw[(long long)(row0 + row) * H + col0] = make_float4(a0, a1, a2, a3);
}

// ---------------- agg layer 1: one wave per node, lane = feature -------------
__global__ void agg1_kernel(const int* __restrict__ rowptr, const int2* __restrict__ edata,
                            const float* __restrict__ xw, const float* __restrict__ dinv,
                            const float* __restrict__ b, float* __restrict__ h1, int N) {
    long long gid = (long long)blockIdx.x * blockDim.x + threadIdx.x;
    int i = (int)(gid >> 6);
    int lane = threadIdx.x & 63;
    if (i >= N) return;
    int start = rowptr[i], end = rowptr[i + 1];
    float acc = 0.f;
    int j = start;
    for (; j + 1 < end; j += 2) {            // 2-way unroll: two gathers in flight
        int2 e0 = edata[j], e1 = edata[j + 1];
        acc = fmaf(xw[(long long)e0.x * H + lane], __int_as_float(e0.y), acc);
        acc = fmaf(xw[(long long)e1.x * H + lane], __int_as_float(e1.y), acc);
    }
    if (j < end) {
        int2 e0 = edata[j];
        acc = fmaf(xw[(long long)e0.x * H + lane], __int_as_float(e0.y), acc);
    }
    float di = dinv[i];
    acc = fmaf(xw[(long long)i * H + lane], di * di, acc);   // self-loop
    acc += b[lane];
    h1[(long long)i * H + lane] = fmaxf(acc, 0.f);           // relu
}

// ---------------- GEMM2: xw2[N,20] = h1[N,64] @ W2[64,20] --------------------
#define G2_ROWS 12
__global__ void gemm2_kernel(const float* __restrict__ h1, const float* __restrict__ W2,
                             float* __restrict__ xw2, int N) {
    __shared__ float hs[G2_ROWS][H + 1];
    __shared__ float ws2[H * C];
    int row0 = blockIdx.x * G2_ROWS;
    for (int t = threadIdx.x; t < H * C; t += 256) ws2[t] = W2[t];
    for (int t = threadIdx.x; t < G2_ROWS * H; t += 256) {
        int r = t >> 6, k = t & 63;
        int row = row0 + r;
        hs[r][k] = (row < N) ? h1[(long long)row * H + k] : 0.f;
    }
    __syncthreads();
    int t = threadIdx.x;
    if (t < G2_ROWS * C) {
        int r = t / C, c = t % C;
        int row = row0 + r;
        if (row < N) {
            float acc = 0.f;
            #pragma unroll
            for (int k = 0; k < H; k++) acc = fmaf(hs[r][k], ws2[k * C + c], acc);
            xw2[(long long)row * C + c] = acc;
        }
    }
}

// ------- agg layer 2 + self-loop + bias + softmax: 2 nodes per wave ----------
__global__ void agg2_final_kernel(const int* __restrict__ rowptr, const int2* __restrict__ edata,
                                  const float* __restrict__ xw2, const float* __restrict__ dinv,
                                  const float* __restrict__ b2, float* __restrict__ out, int N) {
    long long gid = (long long)blockIdx.x * blockDim.x + threadIdx.x;
    int wid = (int)(gid >> 6);
    int half = (threadIdx.x & 63) >> 5;
    int l = threadIdx.x & 31;
    int i = wid * 2 + half;
    float acc = 0.f;
    if (i < N) {
        int start = rowptr[i], end = rowptr[i + 1];
        for (int j = start; j < end; j++) {
            int2 e = edata[j];
            if (l < C)
                acc = fmaf(xw2[(long long)e.x * C + l], __int_as_float(e.y), acc);
        }
        if (l < C) {
            float di = dinv[i];
            acc = fmaf(xw2[(long long)i * C + l], di * di, acc);
            acc += b2[l];
        }
    }
    bool active = (i < N) && (l < C);
    float v = active ? acc : -1e30f;
    float mx = v;
    #pragma unroll
    for (int off = 16; off >= 1; off >>= 1) mx = fmaxf(mx, __shfl_xor(mx, off, 32));
    float ex = active ? expf(v - mx) : 0.f;
    float sm = ex;
    #pragma unroll
    for (int off = 16; off >= 1; off >>= 1) sm += __shfl_xor(sm, off, 32);
    if (active) out[(long long)i * C + l] = ex / sm;
}

// ---------------- launch -----------------------------------------------------
static inline size_t align256(size_t x) { return (x + 255) & ~(size_t)255; }

extern "C" void kernel_launch(void* const* d_in, const int* in_sizes, int n_in,
                              void* d_out, int out_size, void* d_ws, size_t ws_size,
                              hipStream_t stream) {
    const float* x  = (const float*)d_in[0];
    const int*   ei = (const int*)d_in[1];
    const float* ew = (const float*)d_in[2];
    const float* W1 = (const float*)d_in[3];
    const float* b1 = (const float*)d_in[4];
    const float* W2 = (const float*)d_in[5];
    const float* b2 = (const float*)d_in[6];
    float* out = (float*)d_out;

    int N = in_sizes[0] / FIN;   // 100000
    int E = in_sizes[2];         // 3200000
    int NB = (N + 1023) / 1024;  // scan blocks (98)

    char* ws = (char*)d_ws;
    size_t off = 0;
    float* deg    = (float*)(ws + off); off = align256(off + (size_t)N * 4);
    int*   flag   = (int*)(ws + off);   off = align256(off + 4);
    int*   counts = (int*)(ws + off);   off = align256(off + (size_t)N * 4);
    int*   bsum   = (int*)(ws + off);   off = align256(off + (size_t)NB * 4);
    int*   rowptr = (int*)(ws + off);   off = align256(off + (size_t)(N + 1) * 4);
    int*   cursor = (int*)(ws + off);   off = align256(off + (size_t)N * 4);
    int2*  edata  = (int2*)(ws + off);  off = align256(off + (size_t)E * 8);
    float* xw1    = (float*)(ws + off); off = align256(off + (size_t)N * H * 4);
    float* h1     = (float*)(ws + off); off = align256(off + (size_t)N * H * 4);
    float* xw2    = (float*)(ws + off); off = align256(off + (size_t)N * C * 4);

    hipMemsetAsync(counts, 0, (size_t)N * 4, stream);
    hipMemsetAsync(deg,    0, (size_t)N * 4, stream);

    detect_kernel<<<1, 256, 0, stream>>>(ei, 256, flag);
    hist_kernel<<<(E + 255) / 256, 256, 0, stream>>>(ei, ew, counts, deg, E, flag);
    dinv_kernel<<<(N + 255) / 256, 256, 0, stream>>>(deg, N);

    block_sums_kernel<<<NB, 256, 0, stream>>>(counts, bsum, N);
    scan_bsums_kernel<<<1, 256, 0, stream>>>(bsum, NB, rowptr, N, E);
    scan_local_kernel<<<NB, 256, 0, stream>>>(counts, bsum, rowptr, N);

    hipMemcpyAsync(cursor, rowptr, (size_t)N * 4, hipMemcpyDeviceToDevice, stream);
    fill_kernel<<<(E + 255) / 256, 256, 0, stream>>>(ei, ew, deg, cursor, edata, E, flag);

    gemm1_kernel<<<N / G1_ROWS, 256, 0, stream>>>(x, W1, xw1, N);

    agg1_kernel<<<(int)(((long long)N * 64 + 255) / 256), 256, 0, stream>>>(
        rowptr, edata, xw1, deg, b1, h1, N);

    gemm2_kernel<<<(N + G2_ROWS - 1) / G2_ROWS, 256, 0, stream>>>(h1, W2, xw2, N);

    int waves2 = (N + 1) / 2;
    agg2_final_kernel<<<(int)(((long long)waves2 * 64 + 255) / 256), 256, 0, stream>>>(
        rowptr, edata, xw2, deg, b2, out, N);
}

// Round 3
// 1085.264 us; speedup vs baseline: 1.7484x; 1.3191x over previous
//
#include <hip/hip_runtime.h>
#include <math.h>

#define FIN 512
#define H   64
#define C   20

// ---------------- edge-index layout detection ----------------
// int64 little-endian delivery => odd 32-bit words of first entries all zero.
__global__ void detect_kernel(const int* __restrict__ ei, int n_check, int* flag) {
    __shared__ int nz;
    if (threadIdx.x == 0) nz = 0;
    __syncthreads();
    for (int i = threadIdx.x; i < n_check; i += blockDim.x)
        if (ei[2 * i + 1] != 0) nz = 1;   // benign race
    __syncthreads();
    if (threadIdx.x == 0) *flag = (nz == 0) ? 1 : 0;   // 1 => int64 layout
}

__device__ __forceinline__ int edge_val(const int* __restrict__ ei, long long idx, int m64) {
    return m64 ? ei[2 * idx] : ei[(int)idx];
}

// ---------------- histogram: per-dst edge count + weighted degree ------------
__global__ void hist_kernel(const int* __restrict__ ei, const float* __restrict__ ew,
                            int* __restrict__ counts, float* __restrict__ deg,
                            int E, const int* __restrict__ flag) {
    int m64 = *flag;
    int e = blockIdx.x * blockDim.x + threadIdx.x;
    if (e < E) {
        int d = edge_val(ei, (long long)E + e, m64);
        atomicAdd(&counts[d], 1);
        atomicAdd(&deg[d], ew[e]);
    }
}

// dinv = rsqrt(deg + 1)   (self-loop weight 1 => deg always > 0)
__global__ void dinv_kernel(float* __restrict__ deg, int N) {
    int i = blockIdx.x * blockDim.x + threadIdx.x;
    if (i < N) deg[i] = rsqrtf(deg[i] + 1.0f);
}

// ---------------- CSR build: 3-kernel exclusive scan over counts -------------
__global__ void block_sums_kernel(const int* __restrict__ counts, int* __restrict__ bsum, int N) {
    __shared__ int lds[256];
    int t = threadIdx.x;
    int base = blockIdx.x * 1024 + t * 4;
    int s = 0;
    #pragma unroll
    for (int k = 0; k < 4; k++) { int i = base + k; if (i < N) s += counts[i]; }
    lds[t] = s; __syncthreads();
    for (int off = 128; off > 0; off >>= 1) {
        if (t < off) lds[t] += lds[t + off];
        __syncthreads();
    }
    if (t == 0) bsum[blockIdx.x] = lds[0];
}

__global__ void scan_bsums_kernel(int* __restrict__ bsum, int NB,
                                  int* __restrict__ rowptr, int N, int E) {
    __shared__ int lds[1024];
    int t = threadIdx.x;
    for (int i = t; i < NB; i += blockDim.x) lds[i] = bsum[i];
    __syncthreads();
    if (t == 0) {
        int run = 0;
        for (int i = 0; i < NB; i++) { int v = lds[i]; lds[i] = run; run += v; }
        rowptr[N] = E;
    }
    __syncthreads();
    for (int i = t; i < NB; i += blockDim.x) bsum[i] = lds[i];
}

__global__ void scan_local_kernel(const int* __restrict__ counts, const int* __restrict__ bsum,
                                  int* __restrict__ rowptr, int N) {
    __shared__ int lds[256];
    int t = threadIdx.x;
    int base = blockIdx.x * 1024 + t * 4;
    int c[4]; int s = 0;
    #pragma unroll
    for (int k = 0; k < 4; k++) { int i = base + k; c[k] = (i < N) ? counts[i] : 0; s += c[k]; }
    lds[t] = s; __syncthreads();
    for (int off = 1; off < 256; off <<= 1) {
        int add = (t >= off) ? lds[t - off] : 0;
        __syncthreads();
        lds[t] += add;
        __syncthreads();
    }
    int start = bsum[blockIdx.x] + lds[t] - s;
    #pragma unroll
    for (int k = 0; k < 4; k++) {
        int i = base + k;
        if (i < N) { rowptr[i] = start; start += c[k]; }
    }
}

// fill: edata[pos] = {src, norm}  bucketed by dst via atomic cursor
__global__ void fill_kernel(const int* __restrict__ ei, const float* __restrict__ ew,
                            const float* __restrict__ dinv, int* __restrict__ cursor,
                            int2* __restrict__ edata, int E, const int* __restrict__ flag) {
    int m64 = *flag;
    int e = blockIdx.x * blockDim.x + threadIdx.x;
    if (e < E) {
        int s = edge_val(ei, e, m64);
        int d = edge_val(ei, (long long)E + e, m64);
        float norm = dinv[s] * ew[e] * dinv[d];
        int pos = atomicAdd(&cursor[d], 1);
        edata[pos] = make_int2(s, __float_as_int(norm));
    }
}

// ---------------- GEMM1: xw1[N,64] = x[N,512] @ W1[512,64] -------------------
// 128x64 block tile, BK=32, 8x4 register tile per thread, both operands in LDS.
#define BM 128
#define BK 32
#define XPAD 4   // xs row-stride pad: keeps b128 alignment, cuts write conflicts to 4-way
__global__ __launch_bounds__(256, 4) void gemm1_kernel(const float* __restrict__ x,
                                                       const float* __restrict__ W,
                                                       float* __restrict__ xw, int N) {
    __shared__ float xs[BK][BM + XPAD];   // transposed: xs[k][row]
    __shared__ float wsh[BK][H];
    int row0 = blockIdx.x * BM;
    int tid = threadIdx.x;
    int tx = tid & 15;    // cols 4*tx .. 4*tx+3
    int ty = tid >> 4;    // rows 8*ty .. 8*ty+7
    float4 acc[8];
    #pragma unroll
    for (int r = 0; r < 8; r++) acc[r] = make_float4(0.f, 0.f, 0.f, 0.f);

    for (int k0 = 0; k0 < FIN; k0 += BK) {
        // x tile: 128 rows x 32 k = 1024 float4, 4 per thread, transposed into LDS
        #pragma unroll
        for (int l = 0; l < 4; l++) {
            int idx = tid + l * 256;           // 0..1023
            int row = idx >> 3;                // 0..127
            int kq  = idx & 7;                 // which float4 along k
            int grow = row0 + row;
            if (grow >= N) grow = N - 1;       // clamp: dup load, store guarded later
            float4 v = *(const float4*)&x[(long long)grow * FIN + k0 + kq * 4];
            xs[kq * 4 + 0][row] = v.x;
            xs[kq * 4 + 1][row] = v.y;
            xs[kq * 4 + 2][row] = v.z;
            xs[kq * 4 + 3][row] = v.w;
        }
        // W tile: 32 k x 64 = 512 float4, 2 per thread
        #pragma unroll
        for (int l = 0; l < 2; l++) {
            int idx = tid + l * 256;           // 0..511
            int k = idx >> 4;
            int cq = idx & 15;
            *(float4*)&wsh[k][cq * 4] = *(const float4*)&W[(long long)(k0 + k) * H + cq * 4];
        }
        __syncthreads();
        #pragma unroll
        for (int k = 0; k < BK; k++) {
            float4 a0 = *(const float4*)&xs[k][ty * 8];
            float4 a1 = *(const float4*)&xs[k][ty * 8 + 4];
            float4 w  = *(const float4*)&wsh[k][tx * 4];
            acc[0].x = fmaf(a0.x, w.x, acc[0].x); acc[0].y = fmaf(a0.x, w.y, acc[0].y);
            acc[0].z = fmaf(a0.x, w.z, acc[0].z); acc[0].w = fmaf(a0.x, w.w, acc[0].w);
            acc[1].x = fmaf(a0.y, w.x, acc[1].x); acc[1].y = fmaf(a0.y, w.y, acc[1].y);
            acc[1].z = fmaf(a0.y, w.z, acc[1].z); acc[1].w = fmaf(a0.y, w.w, acc[1].w);
            acc[2].x = fmaf(a0.z, w.x, acc[2].x); acc[2].y = fmaf(a0.z, w.y, acc[2].y);
            acc[2].z = fmaf(a0.z, w.z, acc[2].z); acc[2].w = fmaf(a0.z, w.w, acc[2].w);
            acc[3].x = fmaf(a0.w, w.x, acc[3].x); acc[3].y = fmaf(a0.w, w.y, acc[3].y);
            acc[3].z = fmaf(a0.w, w.z, acc[3].z); acc[3].w = fmaf(a0.w, w.w, acc[3].w);
            acc[4].x = fmaf(a1.x, w.x, acc[4].x); acc[4].y = fmaf(a1.x, w.y, acc[4].y);
            acc[4].z = fmaf(a1.x, w.z, acc[4].z); acc[4].w = fmaf(a1.x, w.w, acc[4].w);
            acc[5].x = fmaf(a1.y, w.x, acc[5].x); acc[5].y = fmaf(a1.y, w.y, acc[5].y);
            acc[5].z = fmaf(a1.y, w.z, acc[5].z); acc[5].w = fmaf(a1.y, w.w, acc[5].w);
            acc[6].x = fmaf(a1.z, w.x, acc[6].x); acc[6].y = fmaf(a1.z, w.y, acc[6].y);
            acc[6].z = fmaf(a1.z, w.z, acc[6].z); acc[6].w = fmaf(a1.z, w.w, acc[6].w);
            acc[7].x = fmaf(a1.w, w.x, acc[7].x); acc[7].y = fmaf(a1.w, w.y, acc[7].y);
            acc[7].z = fmaf(a1.w, w.z, acc[7].z); acc[7].w = fmaf(a1.w, w.w, acc[7].w);
        }
        __syncthreads();
    }
    #pragma unroll
    for (int r = 0; r < 8; r++) {
        int grow = row0 + ty * 8 + r;
        if (grow < N) *(float4*)&xw[(long long)grow * H + tx * 4] = acc[r];
    }
}

// ---------------- agg layer 1: one wave per node, lane = feature -------------
__global__ void agg1_kernel(const int* __restrict__ rowptr, const int2* __restrict__ edata,
                            const float* __restrict__ xw, const float* __restrict__ dinv,
                            const float* __restrict__ b, float* __restrict__ h1, int N) {
    long long gid = (long long)blockIdx.x * blockDim.x + threadIdx.x;
    int i = (int)(gid >> 6);
    int lane = threadIdx.x & 63;
    if (i >= N) return;
    int start = rowptr[i], end = rowptr[i + 1];
    float acc = 0.f;
    int j = start;
    for (; j + 3 < end; j += 4) {            // 4-way unroll: four gathers in flight
        int2 e0 = edata[j], e1 = edata[j + 1], e2 = edata[j + 2], e3 = edata[j + 3];
        float v0 = xw[(long long)e0.x * H + lane];
        float v1 = xw[(long long)e1.x * H + lane];
        float v2 = xw[(long long)e2.x * H + lane];
        float v3 = xw[(long long)e3.x * H + lane];
        acc = fmaf(v0, __int_as_float(e0.y), acc);
        acc = fmaf(v1, __int_as_float(e1.y), acc);
        acc = fmaf(v2, __int_as_float(e2.y), acc);
        acc = fmaf(v3, __int_as_float(e3.y), acc);
    }
    for (; j < end; j++) {
        int2 e0 = edata[j];
        acc = fmaf(xw[(long long)e0.x * H + lane], __int_as_float(e0.y), acc);
    }
    float di = dinv[i];
    acc = fmaf(xw[(long long)i * H + lane], di * di, acc);   // self-loop
    acc += b[lane];
    h1[(long long)i * H + lane] = fmaxf(acc, 0.f);           // relu
}

// ---------------- GEMM2: xw2[N,20] = h1[N,64] @ W2[64,20] --------------------
#define G2_ROWS 12
__global__ void gemm2_kernel(const float* __restrict__ h1, const float* __restrict__ W2,
                             float* __restrict__ xw2, int N) {
    __shared__ float hs[G2_ROWS][H + 1];
    __shared__ float ws2[H * C];
    int row0 = blockIdx.x * G2_ROWS;
    for (int t = threadIdx.x; t < H * C; t += 256) ws2[t] = W2[t];
    for (int t = threadIdx.x; t < G2_ROWS * H; t += 256) {
        int r = t >> 6, k = t & 63;
        int row = row0 + r;
        hs[r][k] = (row < N) ? h1[(long long)row * H + k] : 0.f;
    }
    __syncthreads();
    int t = threadIdx.x;
    if (t < G2_ROWS * C) {
        int r = t / C, c = t % C;
        int row = row0 + r;
        if (row < N) {
            float acc = 0.f;
            #pragma unroll
            for (int k = 0; k < H; k++) acc = fmaf(hs[r][k], ws2[k * C + c], acc);
            xw2[(long long)row * C + c] = acc;
        }
    }
}

// ------- agg layer 2 + self-loop + bias + softmax: 2 nodes per wave ----------
__global__ void agg2_final_kernel(const int* __restrict__ rowptr, const int2* __restrict__ edata,
                                  const float* __restrict__ xw2, const float* __restrict__ dinv,
                                  const float* __restrict__ b2, float* __restrict__ out, int N) {
    long long gid = (long long)blockIdx.x * blockDim.x + threadIdx.x;
    int wid = (int)(gid >> 6);
    int half = (threadIdx.x & 63) >> 5;
    int l = threadIdx.x & 31;
    int i = wid * 2 + half;
    float acc = 0.f;
    if (i < N) {
        int start = rowptr[i], end = rowptr[i + 1];
        for (int j = start; j < end; j++) {
            int2 e = edata[j];
            if (l < C)
                acc = fmaf(xw2[(long long)e.x * C + l], __int_as_float(e.y), acc);
        }
        if (l < C) {
            float di = dinv[i];
            acc = fmaf(xw2[(long long)i * C + l], di * di, acc);
            acc += b2[l];
        }
    }
    bool active = (i < N) && (l < C);
    float v = active ? acc : -1e30f;
    float mx = v;
    #pragma unroll
    for (int off = 16; off >= 1; off >>= 1) mx = fmaxf(mx, __shfl_xor(mx, off, 32));
    float ex = active ? expf(v - mx) : 0.f;
    float sm = ex;
    #pragma unroll
    for (int off = 16; off >= 1; off >>= 1) sm += __shfl_xor(sm, off, 32);
    if (active) out[(long long)i * C + l] = ex / sm;
}

// ---------------- launch -----------------------------------------------------
static inline size_t align256(size_t x) { return (x + 255) & ~(size_t)255; }

extern "C" void kernel_launch(void* const* d_in, const int* in_sizes, int n_in,
                              void* d_out, int out_size, void* d_ws, size_t ws_size,
                              hipStream_t stream) {
    const float* x  = (const float*)d_in[0];
    const int*   ei = (const int*)d_in[1];
    const float* ew = (const float*)d_in[2];
    const float* W1 = (const float*)d_in[3];
    const float* b1 = (const float*)d_in[4];
    const float* W2 = (const float*)d_in[5];
    const float* b2 = (const float*)d_in[6];
    float* out = (float*)d_out;

    int N = in_sizes[0] / FIN;   // 100000
    int E = in_sizes[2];         // 3200000
    int NB = (N + 1023) / 1024;  // scan blocks (98)

    char* ws = (char*)d_ws;
    size_t off = 0;
    float* deg    = (float*)(ws + off); off = align256(off + (size_t)N * 4);
    int*   flag   = (int*)(ws + off);   off = align256(off + 4);
    int*   counts = (int*)(ws + off);   off = align256(off + (size_t)N * 4);
    int*   bsum   = (int*)(ws + off);   off = align256(off + (size_t)NB * 4);
    int*   rowptr = (int*)(ws + off);   off = align256(off + (size_t)(N + 1) * 4);
    int*   cursor = (int*)(ws + off);   off = align256(off + (size_t)N * 4);
    int2*  edata  = (int2*)(ws + off);  off = align256(off + (size_t)E * 8);
    float* xw1    = (float*)(ws + off); off = align256(off + (size_t)N * H * 4);
    float* h1     = (float*)(ws + off); off = align256(off + (size_t)N * H * 4);
    float* xw2    = (float*)(ws + off); off = align256(off + (size_t)N * C * 4);

    hipMemsetAsync(counts, 0, (size_t)N * 4, stream);
    hipMemsetAsync(deg,    0, (size_t)N * 4, stream);

    detect_kernel<<<1, 256, 0, stream>>>(ei, 256, flag);
    hist_kernel<<<(E + 255) / 256, 256, 0, stream>>>(ei, ew, counts, deg, E, flag);
    dinv_kernel<<<(N + 255) / 256, 256, 0, stream>>>(deg, N);

    block_sums_kernel<<<NB, 256, 0, stream>>>(counts, bsum, N);
    scan_bsums_kernel<<<1, 256, 0, stream>>>(bsum, NB, rowptr, N, E);
    scan_local_kernel<<<NB, 256, 0, stream>>>(counts, bsum, rowptr, N);

    hipMemcpyAsync(cursor, rowptr, (size_t)N * 4, hipMemcpyDeviceToDevice, stream);
    fill_kernel<<<(E + 255) / 256, 256, 0, stream>>>(ei, ew, deg, cursor, edata, E, flag);

    gemm1_kernel<<<(N + BM - 1) / BM, 256, 0, stream>>>(x, W1, xw1, N);

    agg1_kernel<<<(int)(((long long)N * 64 + 255) / 256), 256, 0, stream>>>(
        rowptr, edata, xw1, deg, b1, h1, N);

    gemm2_kernel<<<(N + G2_ROWS - 1) / G2_ROWS, 256, 0, stream>>>(h1, W2, xw2, N);

    int waves2 = (N + 1) / 2;
    agg2_final_kernel<<<(int)(((long long)waves2 * 64 + 255) / 256), 256, 0, stream>>>(
        rowptr, edata, xw2, deg, b2, out, N);
}

// Round 4
// 906.320 us; speedup vs baseline: 2.0936x; 1.1974x over previous
//
#include <hip/hip_runtime.h>
#include <math.h>

#define FIN 512
#define H   64
#define C   20

// ---------------- edge-index layout detection ----------------
// int64 little-endian delivery => odd 32-bit words of first entries all zero.
__global__ void detect_kernel(const int* __restrict__ ei, int n_check, int* flag) {
    __shared__ int nz;
    if (threadIdx.x == 0) nz = 0;
    __syncthreads();
    for (int i = threadIdx.x; i < n_check; i += blockDim.x)
        if (ei[2 * i + 1] != 0) nz = 1;   // benign race
    __syncthreads();
    if (threadIdx.x == 0) *flag = (nz == 0) ? 1 : 0;   // 1 => int64 layout
}

__device__ __forceinline__ int edge_val(const int* __restrict__ ei, long long idx, int m64) {
    return m64 ? ei[2 * idx] : ei[(int)idx];
}

// ---------------- histogram+rank: ONE u64 atomic per edge --------------------
// packed[d]: bits 40..63 = edge count, bits 0..39 = fixed-point (2^-28) sum of ew.
// Return value's count field = this edge's rank within its dst bucket.
#define FIXSCALE 268435456.0f   // 2^28
__global__ void histrank_kernel(const int* __restrict__ ei, const float* __restrict__ ew,
                                unsigned long long* __restrict__ packed, int* __restrict__ rank,
                                int E, const int* __restrict__ flag) {
    int m64 = *flag;
    int e = blockIdx.x * blockDim.x + threadIdx.x;
    if (e < E) {
        int d = edge_val(ei, (long long)E + e, m64);
        unsigned long long add = (1ULL << 40) |
            (unsigned long long)(ew[e] * FIXSCALE + 0.5f);
        unsigned long long old = atomicAdd(&packed[d], add);
        rank[e] = (int)(old >> 40);
    }
}

// unpack: counts for the scan, dinv = rsqrt(deg + 1) (self-loop weight 1)
__global__ void dinv_extract_kernel(const unsigned long long* __restrict__ packed,
                                    float* __restrict__ dinv, int* __restrict__ counts, int N) {
    int i = blockIdx.x * blockDim.x + threadIdx.x;
    if (i < N) {
        unsigned long long v = packed[i];
        counts[i] = (int)(v >> 40);
        float deg = (float)((double)(v & ((1ULL << 40) - 1)) * (1.0 / 268435456.0));
        dinv[i] = rsqrtf(deg + 1.0f);
    }
}

// ---------------- CSR build: 3-kernel exclusive scan over counts -------------
__global__ void block_sums_kernel(const int* __restrict__ counts, int* __restrict__ bsum, int N) {
    __shared__ int lds[256];
    int t = threadIdx.x;
    int base = blockIdx.x * 1024 + t * 4;
    int s = 0;
    #pragma unroll
    for (int k = 0; k < 4; k++) { int i = base + k; if (i < N) s += counts[i]; }
    lds[t] = s; __syncthreads();
    for (int off = 128; off > 0; off >>= 1) {
        if (t < off) lds[t] += lds[t + off];
        __syncthreads();
    }
    if (t == 0) bsum[blockIdx.x] = lds[0];
}

__global__ void scan_bsums_kernel(int* __restrict__ bsum, int NB,
                                  int* __restrict__ rowptr, int N, int E) {
    __shared__ int lds[1024];
    int t = threadIdx.x;
    for (int i = t; i < NB; i += blockDim.x) lds[i] = bsum[i];
    __syncthreads();
    if (t == 0) {
        int run = 0;
        for (int i = 0; i < NB; i++) { int v = lds[i]; lds[i] = run; run += v; }
        rowptr[N] = E;
    }
    __syncthreads();
    for (int i = t; i < NB; i += blockDim.x) bsum[i] = lds[i];
}

__global__ void scan_local_kernel(const int* __restrict__ counts, const int* __restrict__ bsum,
                                  int* __restrict__ rowptr, int N) {
    __shared__ int lds[256];
    int t = threadIdx.x;
    int base = blockIdx.x * 1024 + t * 4;
    int c[4]; int s = 0;
    #pragma unroll
    for (int k = 0; k < 4; k++) { int i = base + k; c[k] = (i < N) ? counts[i] : 0; s += c[k]; }
    lds[t] = s; __syncthreads();
    for (int off = 1; off < 256; off <<= 1) {
        int add = (t >= off) ? lds[t - off] : 0;
        __syncthreads();
        lds[t] += add;
        __syncthreads();
    }
    int start = bsum[blockIdx.x] + lds[t] - s;
    #pragma unroll
    for (int k = 0; k < 4; k++) {
        int i = base + k;
        if (i < N) { rowptr[i] = start; start += c[k]; }
    }
}

// fill (no atomics): edata[rowptr[d] + rank[e]] = {src, norm}
__global__ void fill2_kernel(const int* __restrict__ ei, const float* __restrict__ ew,
                             const float* __restrict__ dinv, const int* __restrict__ rowptr,
                             const int* __restrict__ rank, int2* __restrict__ edata,
                             int E, const int* __restrict__ flag) {
    int m64 = *flag;
    int e = blockIdx.x * blockDim.x + threadIdx.x;
    if (e < E) {
        int s = edge_val(ei, e, m64);
        int d = edge_val(ei, (long long)E + e, m64);
        float norm = dinv[s] * ew[e] * dinv[d];
        edata[rowptr[d] + rank[e]] = make_int2(s, __float_as_int(norm));
    }
}

// ---------------- GEMM1: xw1[N,64] = x[N,512] @ W1[512,64] -------------------
// 128x64 block tile, BK=32, 8x4 register tile per thread, both operands in LDS.
#define BM 128
#define BK 32
#define XPAD 4
__global__ __launch_bounds__(256, 4) void gemm1_kernel(const float* __restrict__ x,
                                                       const float* __restrict__ W,
                                                       float* __restrict__ xw, int N) {
    __shared__ float xs[BK][BM + XPAD];   // transposed: xs[k][row]
    __shared__ float wsh[BK][H];
    int row0 = blockIdx.x * BM;
    int tid = threadIdx.x;
    int tx = tid & 15;    // cols 4*tx .. 4*tx+3
    int ty = tid >> 4;    // rows 8*ty .. 8*ty+7
    float4 acc[8];
    #pragma unroll
    for (int r = 0; r < 8; r++) acc[r] = make_float4(0.f, 0.f, 0.f, 0.f);

    for (int k0 = 0; k0 < FIN; k0 += BK) {
        #pragma unroll
        for (int l = 0; l < 4; l++) {
            int idx = tid + l * 256;           // 0..1023
            int row = idx >> 3;                // 0..127
            int kq  = idx & 7;
            int grow = row0 + row;
            if (grow >= N) grow = N - 1;
            float4 v = *(const float4*)&x[(long long)grow * FIN + k0 + kq * 4];
            xs[kq * 4 + 0][row] = v.x;
            xs[kq * 4 + 1][row] = v.y;
            xs[kq * 4 + 2][row] = v.z;
            xs[kq * 4 + 3][row] = v.w;
        }
        #pragma unroll
        for (int l = 0; l < 2; l++) {
            int idx = tid + l * 256;           // 0..511
            int k = idx >> 4;
            int cq = idx & 15;
            *(float4*)&wsh[k][cq * 4] = *(const float4*)&W[(long long)(k0 + k) * H + cq * 4];
        }
        __syncthreads();
        #pragma unroll
        for (int k = 0; k < BK; k++) {
            float4 a0 = *(const float4*)&xs[k][ty * 8];
            float4 a1 = *(const float4*)&xs[k][ty * 8 + 4];
            float4 w  = *(const float4*)&wsh[k][tx * 4];
            acc[0].x = fmaf(a0.x, w.x, acc[0].x); acc[0].y = fmaf(a0.x, w.y, acc[0].y);
            acc[0].z = fmaf(a0.x, w.z, acc[0].z); acc[0].w = fmaf(a0.x, w.w, acc[0].w);
            acc[1].x = fmaf(a0.y, w.x, acc[1].x); acc[1].y = fmaf(a0.y, w.y, acc[1].y);
            acc[1].z = fmaf(a0.y, w.z, acc[1].z); acc[1].w = fmaf(a0.y, w.w, acc[1].w);
            acc[2].x = fmaf(a0.z, w.x, acc[2].x); acc[2].y = fmaf(a0.z, w.y, acc[2].y);
            acc[2].z = fmaf(a0.z, w.z, acc[2].z); acc[2].w = fmaf(a0.z, w.w, acc[2].w);
            acc[3].x = fmaf(a0.w, w.x, acc[3].x); acc[3].y = fmaf(a0.w, w.y, acc[3].y);
            acc[3].z = fmaf(a0.w, w.z, acc[3].z); acc[3].w = fmaf(a0.w, w.w, acc[3].w);
            acc[4].x = fmaf(a1.x, w.x, acc[4].x); acc[4].y = fmaf(a1.x, w.y, acc[4].y);
            acc[4].z = fmaf(a1.x, w.z, acc[4].z); acc[4].w = fmaf(a1.x, w.w, acc[4].w);
            acc[5].x = fmaf(a1.y, w.x, acc[5].x); acc[5].y = fmaf(a1.y, w.y, acc[5].y);
            acc[5].z = fmaf(a1.y, w.z, acc[5].z); acc[5].w = fmaf(a1.y, w.w, acc[5].w);
            acc[6].x = fmaf(a1.z, w.x, acc[6].x); acc[6].y = fmaf(a1.z, w.y, acc[6].y);
            acc[6].z = fmaf(a1.z, w.z, acc[6].z); acc[6].w = fmaf(a1.z, w.w, acc[6].w);
            acc[7].x = fmaf(a1.w, w.x, acc[7].x); acc[7].y = fmaf(a1.w, w.y, acc[7].y);
            acc[7].z = fmaf(a1.w, w.z, acc[7].z); acc[7].w = fmaf(a1.w, w.w, acc[7].w);
        }
        __syncthreads();
    }
    #pragma unroll
    for (int r = 0; r < 8; r++) {
        int grow = row0 + ty * 8 + r;
        if (grow < N) *(float4*)&xw[(long long)grow * H + tx * 4] = acc[r];
    }
}

// ---------------- agg layer 1: one wave per node, lane = feature -------------
__global__ void agg1_kernel(const int* __restrict__ rowptr, const int2* __restrict__ edata,
                            const float* __restrict__ xw, const float* __restrict__ dinv,
                            const float* __restrict__ b, float* __restrict__ h1, int N) {
    long long gid = (long long)blockIdx.x * blockDim.x + threadIdx.x;
    int i = (int)(gid >> 6);
    int lane = threadIdx.x & 63;
    if (i >= N) return;
    int start = rowptr[i], end = rowptr[i + 1];
    float acc = 0.f;
    int j = start;
    for (; j + 3 < end; j += 4) {
        int2 e0 = edata[j], e1 = edata[j + 1], e2 = edata[j + 2], e3 = edata[j + 3];
        float v0 = xw[(long long)e0.x * H + lane];
        float v1 = xw[(long long)e1.x * H + lane];
        float v2 = xw[(long long)e2.x * H + lane];
        float v3 = xw[(long long)e3.x * H + lane];
        acc = fmaf(v0, __int_as_float(e0.y), acc);
        acc = fmaf(v1, __int_as_float(e1.y), acc);
        acc = fmaf(v2, __int_as_float(e2.y), acc);
        acc = fmaf(v3, __int_as_float(e3.y), acc);
    }
    for (; j < end; j++) {
        int2 e0 = edata[j];
        acc = fmaf(xw[(long long)e0.x * H + lane], __int_as_float(e0.y), acc);
    }
    float di = dinv[i];
    acc = fmaf(xw[(long long)i * H + lane], di * di, acc);   // self-loop
    acc += b[lane];
    h1[(long long)i * H + lane] = fmaxf(acc, 0.f);           // relu
}

// ---------------- GEMM2: xw2[N,20] = h1[N,64] @ W2[64,20] --------------------
#define G2_ROWS 12
__global__ void gemm2_kernel(const float* __restrict__ h1, const float* __restrict__ W2,
                             float* __restrict__ xw2, int N) {
    __shared__ float hs[G2_ROWS][H + 1];
    __shared__ float ws2[H * C];
    int row0 = blockIdx.x * G2_ROWS;
    for (int t = threadIdx.x; t < H * C; t += 256) ws2[t] = W2[t];
    for (int t = threadIdx.x; t < G2_ROWS * H; t += 256) {
        int r = t >> 6, k = t & 63;
        int row = row0 + r;
        hs[r][k] = (row < N) ? h1[(long long)row * H + k] : 0.f;
    }
    __syncthreads();
    int t = threadIdx.x;
    if (t < G2_ROWS * C) {
        int r = t / C, c = t % C;
        int row = row0 + r;
        if (row < N) {
            float acc = 0.f;
            #pragma unroll
            for (int k = 0; k < H; k++) acc = fmaf(hs[r][k], ws2[k * C + c], acc);
            xw2[(long long)row * C + c] = acc;
        }
    }
}

// ------- agg layer 2 + self-loop + bias + softmax: 2 nodes per wave ----------
__global__ void agg2_final_kernel(const int* __restrict__ rowptr, const int2* __restrict__ edata,
                                  const float* __restrict__ xw2, const float* __restrict__ dinv,
                                  const float* __restrict__ b2, float* __restrict__ out, int N) {
    long long gid = (long long)blockIdx.x * blockDim.x + threadIdx.x;
    int wid = (int)(gid >> 6);
    int half = (threadIdx.x & 63) >> 5;
    int l = threadIdx.x & 31;
    int i = wid * 2 + half;
    float acc = 0.f;
    if (i < N) {
        int start = rowptr[i], end = rowptr[i + 1];
        for (int j = start; j < end; j++) {
            int2 e = edata[j];
            if (l < C)
                acc = fmaf(xw2[(long long)e.x * C + l], __int_as_float(e.y), acc);
        }
        if (l < C) {
            float di = dinv[i];
            acc = fmaf(xw2[(long long)i * C + l], di * di, acc);
            acc += b2[l];
        }
    }
    bool active = (i < N) && (l < C);
    float v = active ? acc : -1e30f;
    float mx = v;
    #pragma unroll
    for (int off = 16; off >= 1; off >>= 1) mx = fmaxf(mx, __shfl_xor(mx, off, 32));
    float ex = active ? expf(v - mx) : 0.f;
    float sm = ex;
    #pragma unroll
    for (int off = 16; off >= 1; off >>= 1) sm += __shfl_xor(sm, off, 32);
    if (active) out[(long long)i * C + l] = ex / sm;
}

// ---------------- launch -----------------------------------------------------
static inline size_t align256(size_t x) { return (x + 255) & ~(size_t)255; }

extern "C" void kernel_launch(void* const* d_in, const int* in_sizes, int n_in,
                              void* d_out, int out_size, void* d_ws, size_t ws_size,
                              hipStream_t stream) {
    const float* x  = (const float*)d_in[0];
    const int*   ei = (const int*)d_in[1];
    const float* ew = (const float*)d_in[2];
    const float* W1 = (const float*)d_in[3];
    const float* b1 = (const float*)d_in[4];
    const float* W2 = (const float*)d_in[5];
    const float* b2 = (const float*)d_in[6];
    float* out = (float*)d_out;

    int N = in_sizes[0] / FIN;   // 100000
    int E = in_sizes[2];         // 3200000
    int NB = (N + 1023) / 1024;  // scan blocks (98)

    char* ws = (char*)d_ws;
    size_t off = 0;
    unsigned long long* packed = (unsigned long long*)(ws + off); off = align256(off + (size_t)N * 8);
    float* dinv   = (float*)(ws + off); off = align256(off + (size_t)N * 4);
    int*   flag   = (int*)(ws + off);   off = align256(off + 4);
    int*   counts = (int*)(ws + off);   off = align256(off + (size_t)N * 4);
    int*   bsum   = (int*)(ws + off);   off = align256(off + (size_t)NB * 4);
    int*   rowptr = (int*)(ws + off);   off = align256(off + (size_t)(N + 1) * 4);
    int2*  edata  = (int2*)(ws + off);  off = align256(off + (size_t)E * 8);
    float* xw1    = (float*)(ws + off); off = align256(off + (size_t)N * H * 4);
    float* h1     = (float*)(ws + off); off = align256(off + (size_t)N * H * 4);
    float* xw2    = (float*)(ws + off); off = align256(off + (size_t)N * C * 4);
    // rank overlays h1: rank is dead before agg1 writes h1 (E*4 = 12.8MB < N*H*4 = 25.6MB)
    int* rank = (int*)h1;

    hipMemsetAsync(packed, 0, (size_t)N * 8, stream);

    detect_kernel<<<1, 256, 0, stream>>>(ei, 256, flag);
    histrank_kernel<<<(E + 255) / 256, 256, 0, stream>>>(ei, ew, packed, rank, E, flag);
    dinv_extract_kernel<<<(N + 255) / 256, 256, 0, stream>>>(packed, dinv, counts, N);

    block_sums_kernel<<<NB, 256, 0, stream>>>(counts, bsum, N);
    scan_bsums_kernel<<<1, 256, 0, stream>>>(bsum, NB, rowptr, N, E);
    scan_local_kernel<<<NB, 256, 0, stream>>>(counts, bsum, rowptr, N);

    fill2_kernel<<<(E + 255) / 256, 256, 0, stream>>>(ei, ew, dinv, rowptr, rank, edata, E, flag);

    gemm1_kernel<<<(N + BM - 1) / BM, 256, 0, stream>>>(x, W1, xw1, N);

    agg1_kernel<<<(int)(((long long)N * 64 + 255) / 256), 256, 0, stream>>>(
        rowptr, edata, xw1, dinv, b1, h1, N);

    gemm2_kernel<<<(N + G2_ROWS - 1) / G2_ROWS, 256, 0, stream>>>(h1, W2, xw2, N);

    int waves2 = (N + 1) / 2;
    agg2_final_kernel<<<(int)(((long long)waves2 * 64 + 255) / 256), 256, 0, stream>>>(
        rowptr, edata, xw2, dinv, b2, out, N);
}

// Round 5
// 799.316 us; speedup vs baseline: 2.3738x; 1.1339x over previous
//
#include <hip/hip_runtime.h>
#include <hip/hip_fp16.h>
#include <math.h>

#define FIN 512
#define H   64
#define C   20

// ---------------- edge-index layout detection ----------------
// int64 little-endian delivery => odd 32-bit words of first entries all zero.
__global__ void detect_kernel(const int* __restrict__ ei, int n_check, int* flag) {
    __shared__ int nz;
    if (threadIdx.x == 0) nz = 0;
    __syncthreads();
    for (int i = threadIdx.x; i < n_check; i += blockDim.x)
        if (ei[2 * i + 1] != 0) nz = 1;   // benign race
    __syncthreads();
    if (threadIdx.x == 0) *flag = (nz == 0) ? 1 : 0;   // 1 => int64 layout
}

__device__ __forceinline__ int edge_val(const int* __restrict__ ei, long long idx, int m64) {
    return m64 ? ei[2 * idx] : ei[(int)idx];
}

// ---------------- histogram+rank: ONE u64 atomic per edge --------------------
// packed[d]: bits 40..63 = edge count, bits 0..39 = fixed-point (2^-28) sum of ew.
#define FIXSCALE 268435456.0f   // 2^28
__global__ void histrank_kernel(const int* __restrict__ ei, const float* __restrict__ ew,
                                unsigned long long* __restrict__ packed, int* __restrict__ rank,
                                int E, const int* __restrict__ flag) {
    int m64 = *flag;
    int e = blockIdx.x * blockDim.x + threadIdx.x;
    if (e < E) {
        int d = edge_val(ei, (long long)E + e, m64);
        unsigned long long add = (1ULL << 40) |
            (unsigned long long)(ew[e] * FIXSCALE + 0.5f);
        unsigned long long old = atomicAdd(&packed[d], add);
        rank[e] = (int)(old >> 40);
    }
}

// unpack: counts for the scan, dinv = rsqrt(deg + 1) (self-loop weight 1)
__global__ void dinv_extract_kernel(const unsigned long long* __restrict__ packed,
                                    float* __restrict__ dinv, int* __restrict__ counts, int N) {
    int i = blockIdx.x * blockDim.x + threadIdx.x;
    if (i < N) {
        unsigned long long v = packed[i];
        counts[i] = (int)(v >> 40);
        float deg = (float)((double)(v & ((1ULL << 40) - 1)) * (1.0 / 268435456.0));
        dinv[i] = rsqrtf(deg + 1.0f);
    }
}

// ---------------- CSR build: 3-kernel exclusive scan over counts -------------
__global__ void block_sums_kernel(const int* __restrict__ counts, int* __restrict__ bsum, int N) {
    __shared__ int lds[256];
    int t = threadIdx.x;
    int base = blockIdx.x * 1024 + t * 4;
    int s = 0;
    #pragma unroll
    for (int k = 0; k < 4; k++) { int i = base + k; if (i < N) s += counts[i]; }
    lds[t] = s; __syncthreads();
    for (int off = 128; off > 0; off >>= 1) {
        if (t < off) lds[t] += lds[t + off];
        __syncthreads();
    }
    if (t == 0) bsum[blockIdx.x] = lds[0];
}

__global__ void scan_bsums_kernel(int* __restrict__ bsum, int NB,
                                  int* __restrict__ rowptr, int N, int E) {
    __shared__ int lds[1024];
    int t = threadIdx.x;
    for (int i = t; i < NB; i += blockDim.x) lds[i] = bsum[i];
    __syncthreads();
    if (t == 0) {
        int run = 0;
        for (int i = 0; i < NB; i++) { int v = lds[i]; lds[i] = run; run += v; }
        rowptr[N] = E;
    }
    __syncthreads();
    for (int i = t; i < NB; i += blockDim.x) bsum[i] = lds[i];
}

__global__ void scan_local_kernel(const int* __restrict__ counts, const int* __restrict__ bsum,
                                  int* __restrict__ rowptr, int N) {
    __shared__ int lds[256];
    int t = threadIdx.x;
    int base = blockIdx.x * 1024 + t * 4;
    int c[4]; int s = 0;
    #pragma unroll
    for (int k = 0; k < 4; k++) { int i = base + k; c[k] = (i < N) ? counts[i] : 0; s += c[k]; }
    lds[t] = s; __syncthreads();
    for (int off = 1; off < 256; off <<= 1) {
        int add = (t >= off) ? lds[t - off] : 0;
        __syncthreads();
        lds[t] += add;
        __syncthreads();
    }
    int start = bsum[blockIdx.x] + lds[t] - s;
    #pragma unroll
    for (int k = 0; k < 4; k++) {
        int i = base + k;
        if (i < N) { rowptr[i] = start; start += c[k]; }
    }
}

// fill (no atomics): edata[rowptr[d] + rank[e]] = {src, norm}
__global__ void fill2_kernel(const int* __restrict__ ei, const float* __restrict__ ew,
                             const float* __restrict__ dinv, const int* __restrict__ rowptr,
                             const int* __restrict__ rank, int2* __restrict__ edata,
                             int E, const int* __restrict__ flag) {
    int m64 = *flag;
    int e = blockIdx.x * blockDim.x + threadIdx.x;
    if (e < E) {
        int s = edge_val(ei, e, m64);
        int d = edge_val(ei, (long long)E + e, m64);
        float norm = dinv[s] * ew[e] * dinv[d];
        edata[rowptr[d] + rank[e]] = make_int2(s, __float_as_int(norm));
    }
}

// ---------------- GEMM1: xw1[N,64] = x[N,512] @ W1[512,64], fp16 out ---------
#define BM 128
#define BK 32
#define XPAD 4
__global__ __launch_bounds__(256, 4) void gemm1_kernel(const float* __restrict__ x,
                                                       const float* __restrict__ W,
                                                       __half* __restrict__ xwh, int N) {
    __shared__ float xs[BK][BM + XPAD];   // transposed: xs[k][row]
    __shared__ float wsh[BK][H];
    int row0 = blockIdx.x * BM;
    int tid = threadIdx.x;
    int tx = tid & 15;    // cols 4*tx .. 4*tx+3
    int ty = tid >> 4;    // rows 8*ty .. 8*ty+7
    float4 acc[8];
    #pragma unroll
    for (int r = 0; r < 8; r++) acc[r] = make_float4(0.f, 0.f, 0.f, 0.f);

    for (int k0 = 0; k0 < FIN; k0 += BK) {
        #pragma unroll
        for (int l = 0; l < 4; l++) {
            int idx = tid + l * 256;           // 0..1023
            int row = idx >> 3;                // 0..127
            int kq  = idx & 7;
            int grow = row0 + row;
            if (grow >= N) grow = N - 1;
            float4 v = *(const float4*)&x[(long long)grow * FIN + k0 + kq * 4];
            xs[kq * 4 + 0][row] = v.x;
            xs[kq * 4 + 1][row] = v.y;
            xs[kq * 4 + 2][row] = v.z;
            xs[kq * 4 + 3][row] = v.w;
        }
        #pragma unroll
        for (int l = 0; l < 2; l++) {
            int idx = tid + l * 256;           // 0..511
            int k = idx >> 4;
            int cq = idx & 15;
            *(float4*)&wsh[k][cq * 4] = *(const float4*)&W[(long long)(k0 + k) * H + cq * 4];
        }
        __syncthreads();
        #pragma unroll
        for (int k = 0; k < BK; k++) {
            float4 a0 = *(const float4*)&xs[k][ty * 8];
            float4 a1 = *(const float4*)&xs[k][ty * 8 + 4];
            float4 w  = *(const float4*)&wsh[k][tx * 4];
            acc[0].x = fmaf(a0.x, w.x, acc[0].x); acc[0].y = fmaf(a0.x, w.y, acc[0].y);
            acc[0].z = fmaf(a0.x, w.z, acc[0].z); acc[0].w = fmaf(a0.x, w.w, acc[0].w);
            acc[1].x = fmaf(a0.y, w.x, acc[1].x); acc[1].y = fmaf(a0.y, w.y, acc[1].y);
            acc[1].z = fmaf(a0.y, w.z, acc[1].z); acc[1].w = fmaf(a0.y, w.w, acc[1].w);
            acc[2].x = fmaf(a0.z, w.x, acc[2].x); acc[2].y = fmaf(a0.z, w.y, acc[2].y);
            acc[2].z = fmaf(a0.z, w.z, acc[2].z); acc[2].w = fmaf(a0.z, w.w, acc[2].w);
            acc[3].x = fmaf(a0.w, w.x, acc[3].x); acc[3].y = fmaf(a0.w, w.y, acc[3].y);
            acc[3].z = fmaf(a0.w, w.z, acc[3].z); acc[3].w = fmaf(a0.w, w.w, acc[3].w);
            acc[4].x = fmaf(a1.x, w.x, acc[4].x); acc[4].y = fmaf(a1.x, w.y, acc[4].y);
            acc[4].z = fmaf(a1.x, w.z, acc[4].z); acc[4].w = fmaf(a1.x, w.w, acc[4].w);
            acc[5].x = fmaf(a1.y, w.x, acc[5].x); acc[5].y = fmaf(a1.y, w.y, acc[5].y);
            acc[5].z = fmaf(a1.y, w.z, acc[5].z); acc[5].w = fmaf(a1.y, w.w, acc[5].w);
            acc[6].x = fmaf(a1.z, w.x, acc[6].x); acc[6].y = fmaf(a1.z, w.y, acc[6].y);
            acc[6].z = fmaf(a1.z, w.z, acc[6].z); acc[6].w = fmaf(a1.z, w.w, acc[6].w);
            acc[7].x = fmaf(a1.w, w.x, acc[7].x); acc[7].y = fmaf(a1.w, w.y, acc[7].y);
            acc[7].z = fmaf(a1.w, w.z, acc[7].z); acc[7].w = fmaf(a1.w, w.w, acc[7].w);
        }
        __syncthreads();
    }
    #pragma unroll
    for (int r = 0; r < 8; r++) {
        int grow = row0 + ty * 8 + r;
        if (grow < N) {
            __half2* p = (__half2*)&xwh[(long long)grow * H + tx * 4];
            p[0] = __floats2half2_rn(acc[r].x, acc[r].y);
            p[1] = __floats2half2_rn(acc[r].z, acc[r].w);
        }
    }
}

// ---------------- agg layer 1: one wave per node, lane = feature -------------
__global__ void agg1_kernel(const int* __restrict__ rowptr, const int2* __restrict__ edata,
                            const __half* __restrict__ xwh, const float* __restrict__ dinv,
                            const float* __restrict__ b, float* __restrict__ h1, int N) {
    long long gid = (long long)blockIdx.x * blockDim.x + threadIdx.x;
    int i = (int)(gid >> 6);
    int lane = threadIdx.x & 63;
    if (i >= N) return;
    int start = rowptr[i], end = rowptr[i + 1];
    float acc = 0.f;
    int j = start;
    for (; j + 3 < end; j += 4) {
        int2 e0 = edata[j], e1 = edata[j + 1], e2 = edata[j + 2], e3 = edata[j + 3];
        float v0 = __half2float(xwh[(long long)e0.x * H + lane]);
        float v1 = __half2float(xwh[(long long)e1.x * H + lane]);
        float v2 = __half2float(xwh[(long long)e2.x * H + lane]);
        float v3 = __half2float(xwh[(long long)e3.x * H + lane]);
        acc = fmaf(v0, __int_as_float(e0.y), acc);
        acc = fmaf(v1, __int_as_float(e1.y), acc);
        acc = fmaf(v2, __int_as_float(e2.y), acc);
        acc = fmaf(v3, __int_as_float(e3.y), acc);
    }
    for (; j < end; j++) {
        int2 e0 = edata[j];
        acc = fmaf(__half2float(xwh[(long long)e0.x * H + lane]), __int_as_float(e0.y), acc);
    }
    float di = dinv[i];
    acc = fmaf(__half2float(xwh[(long long)i * H + lane]), di * di, acc);   // self-loop
    acc += b[lane];
    h1[(long long)i * H + lane] = fmaxf(acc, 0.f);           // relu
}

// ---------------- GEMM2: xw2[N,20] = h1[N,64] @ W2[64,20], fp16 out ----------
#define G2_ROWS 12
__global__ void gemm2_kernel(const float* __restrict__ h1, const float* __restrict__ W2,
                             __half* __restrict__ xw2h, int N) {
    __shared__ float hs[G2_ROWS][H + 1];
    __shared__ float ws2[H * C];
    int row0 = blockIdx.x * G2_ROWS;
    for (int t = threadIdx.x; t < H * C; t += 256) ws2[t] = W2[t];
    for (int t = threadIdx.x; t < G2_ROWS * H; t += 256) {
        int r = t >> 6, k = t & 63;
        int row = row0 + r;
        hs[r][k] = (row < N) ? h1[(long long)row * H + k] : 0.f;
    }
    __syncthreads();
    int t = threadIdx.x;
    if (t < G2_ROWS * C) {
        int r = t / C, c = t % C;
        int row = row0 + r;
        if (row < N) {
            float acc = 0.f;
            #pragma unroll
            for (int k = 0; k < H; k++) acc = fmaf(hs[r][k], ws2[k * C + c], acc);
            xw2h[(long long)row * C + c] = __float2half(acc);
        }
    }
}

// ------- agg layer 2 + self-loop + bias + softmax: 2 nodes per wave ----------
__global__ void agg2_final_kernel(const int* __restrict__ rowptr, const int2* __restrict__ edata,
                                  const __half* __restrict__ xw2h, const float* __restrict__ dinv,
                                  const float* __restrict__ b2, float* __restrict__ out, int N) {
    long long gid = (long long)blockIdx.x * blockDim.x + threadIdx.x;
    int wid = (int)(gid >> 6);
    int half = (threadIdx.x & 63) >> 5;
    int l = threadIdx.x & 31;
    int i = wid * 2 + half;
    float acc = 0.f;
    bool active = (i < N) && (l < C);
    if (active) {
        int start = rowptr[i], end = rowptr[i + 1];
        int j = start;
        for (; j + 3 < end; j += 4) {
            int2 e0 = edata[j], e1 = edata[j + 1], e2 = edata[j + 2], e3 = edata[j + 3];
            float v0 = __half2float(xw2h[(long long)e0.x * C + l]);
            float v1 = __half2float(xw2h[(long long)e1.x * C + l]);
            float v2 = __half2float(xw2h[(long long)e2.x * C + l]);
            float v3 = __half2float(xw2h[(long long)e3.x * C + l]);
            acc = fmaf(v0, __int_as_float(e0.y), acc);
            acc = fmaf(v1, __int_as_float(e1.y), acc);
            acc = fmaf(v2, __int_as_float(e2.y), acc);
            acc = fmaf(v3, __int_as_float(e3.y), acc);
        }
        for (; j < end; j++) {
            int2 e = edata[j];
            acc = fmaf(__half2float(xw2h[(long long)e.x * C + l]), __int_as_float(e.y), acc);
        }
        float di = dinv[i];
        acc = fmaf(__half2float(xw2h[(long long)i * C + l]), di * di, acc);
        acc += b2[l];
    }
    float v = active ? acc : -1e30f;
    float mx = v;
    #pragma unroll
    for (int off = 16; off >= 1; off >>= 1) mx = fmaxf(mx, __shfl_xor(mx, off, 32));
    float ex = active ? expf(v - mx) : 0.f;
    float sm = ex;
    #pragma unroll
    for (int off = 16; off >= 1; off >>= 1) sm += __shfl_xor(sm, off, 32);
    if (active) out[(long long)i * C + l] = ex / sm;
}

// ---------------- launch -----------------------------------------------------
static inline size_t align256(size_t x) { return (x + 255) & ~(size_t)255; }

extern "C" void kernel_launch(void* const* d_in, const int* in_sizes, int n_in,
                              void* d_out, int out_size, void* d_ws, size_t ws_size,
                              hipStream_t stream) {
    const float* x  = (const float*)d_in[0];
    const int*   ei = (const int*)d_in[1];
    const float* ew = (const float*)d_in[2];
    const float* W1 = (const float*)d_in[3];
    const float* b1 = (const float*)d_in[4];
    const float* W2 = (const float*)d_in[5];
    const float* b2 = (const float*)d_in[6];
    float* out = (float*)d_out;

    int N = in_sizes[0] / FIN;   // 100000
    int E = in_sizes[2];         // 3200000
    int NB = (N + 1023) / 1024;  // scan blocks (98)

    char* ws = (char*)d_ws;
    size_t off = 0;
    unsigned long long* packed = (unsigned long long*)(ws + off); off = align256(off + (size_t)N * 8);
    float*  dinv   = (float*)(ws + off);  off = align256(off + (size_t)N * 4);
    int*    flag   = (int*)(ws + off);    off = align256(off + 4);
    int*    counts = (int*)(ws + off);    off = align256(off + (size_t)N * 4);
    int*    bsum   = (int*)(ws + off);    off = align256(off + (size_t)NB * 4);
    int*    rowptr = (int*)(ws + off);    off = align256(off + (size_t)(N + 1) * 4);
    int2*   edata  = (int2*)(ws + off);   off = align256(off + (size_t)E * 8);
    __half* xw1h   = (__half*)(ws + off); off = align256(off + (size_t)N * H * 2);
    float*  h1     = (float*)(ws + off);  off = align256(off + (size_t)N * H * 4);
    __half* xw2h   = (__half*)(ws + off); off = align256(off + (size_t)N * C * 2);
    // rank overlays h1: rank is dead before agg1 writes h1 (E*4 = 12.8MB < N*H*4 = 25.6MB)
    int* rank = (int*)h1;

    hipMemsetAsync(packed, 0, (size_t)N * 8, stream);

    detect_kernel<<<1, 256, 0, stream>>>(ei, 256, flag);
    histrank_kernel<<<(E + 255) / 256, 256, 0, stream>>>(ei, ew, packed, rank, E, flag);
    dinv_extract_kernel<<<(N + 255) / 256, 256, 0, stream>>>(packed, dinv, counts, N);

    block_sums_kernel<<<NB, 256, 0, stream>>>(counts, bsum, N);
    scan_bsums_kernel<<<1, 256, 0, stream>>>(bsum, NB, rowptr, N, E);
    scan_local_kernel<<<NB, 256, 0, stream>>>(counts, bsum, rowptr, N);

    fill2_kernel<<<(E + 255) / 256, 256, 0, stream>>>(ei, ew, dinv, rowptr, rank, edata, E, flag);

    gemm1_kernel<<<(N + BM - 1) / BM, 256, 0, stream>>>(x, W1, xw1h, N);

    agg1_kernel<<<(int)(((long long)N * 64 + 255) / 256), 256, 0, stream>>>(
        rowptr, edata, xw1h, dinv, b1, h1, N);

    gemm2_kernel<<<(N + G2_ROWS - 1) / G2_ROWS, 256, 0, stream>>>(h1, W2, xw2h, N);

    int waves2 = (N + 1) / 2;
    agg2_final_kernel<<<(int)(((long long)waves2 * 64 + 255) / 256), 256, 0, stream>>>(
        rowptr, edata, xw2h, dinv, b2, out, N);
}

// Round 7
// 777.376 us; speedup vs baseline: 2.4408x; 1.0282x over previous
//
#include <hip/hip_runtime.h>
#include <hip/hip_fp16.h>
#include <math.h>

#define FIN 512
#define H   64
#define C   20

typedef _Float16 half8 __attribute__((ext_vector_type(8)));
typedef float floatx4 __attribute__((ext_vector_type(4)));

// ---------------- inline edge-index layout detection -------------------------
// int64 little-endian delivery => odd 32-bit words of first entries all zero.
// Indices are random in [0,100000): 32 genuine int32 indices all == 0 is impossible.
__device__ __forceinline__ int detect_m64(const int* __restrict__ ei) {
    int nz = 0;
    #pragma unroll
    for (int i = 0; i < 32; i++) nz |= ei[2 * i + 1];
    return nz == 0;   // 1 => int64 layout
}

__device__ __forceinline__ int edge_val(const int* __restrict__ ei, long long idx, int m64) {
    return m64 ? ei[2 * idx] : ei[(int)idx];
}

// ---------------- histogram+rank: ONE u64 atomic per edge --------------------
// packed[d]: bits 40..63 = edge count, bits 0..39 = fixed-point (2^-28) sum of ew.
#define FIXSCALE 268435456.0f   // 2^28
__global__ void histrank_kernel(const int* __restrict__ ei, const float* __restrict__ ew,
                                unsigned long long* __restrict__ packed, int* __restrict__ rank,
                                int E) {
    int m64 = detect_m64(ei);
    int e = blockIdx.x * blockDim.x + threadIdx.x;
    if (e < E) {
        int d = edge_val(ei, (long long)E + e, m64);
        unsigned long long add = (1ULL << 40) |
            (unsigned long long)(ew[e] * FIXSCALE + 0.5f);
        unsigned long long old = atomicAdd(&packed[d], add);
        rank[e] = (int)(old >> 40);
    }
}

// ---------------- CSR build: 3-kernel exclusive scan (reads packed) ----------
__global__ void block_sums_kernel(const unsigned long long* __restrict__ packed,
                                  int* __restrict__ bsum, int N) {
    __shared__ int lds[256];
    int t = threadIdx.x;
    int base = blockIdx.x * 1024 + t * 4;
    int s = 0;
    #pragma unroll
    for (int k = 0; k < 4; k++) { int i = base + k; if (i < N) s += (int)(packed[i] >> 40); }
    lds[t] = s; __syncthreads();
    for (int off = 128; off > 0; off >>= 1) {
        if (t < off) lds[t] += lds[t + off];
        __syncthreads();
    }
    if (t == 0) bsum[blockIdx.x] = lds[0];
}

__global__ void scan_bsums_kernel(int* __restrict__ bsum, int NB,
                                  int* __restrict__ rowptr, int N, int E) {
    __shared__ int lds[1024];
    int t = threadIdx.x;
    for (int i = t; i < NB; i += blockDim.x) lds[i] = bsum[i];
    __syncthreads();
    if (t == 0) {
        int run = 0;
        for (int i = 0; i < NB; i++) { int v = lds[i]; lds[i] = run; run += v; }
        rowptr[N] = E;
    }
    __syncthreads();
    for (int i = t; i < NB; i += blockDim.x) bsum[i] = lds[i];
}

// also emits dinv = rsqrt(deg + 1) (self-loop weight 1)
__global__ void scan_local_kernel(const unsigned long long* __restrict__ packed,
                                  const int* __restrict__ bsum,
                                  int* __restrict__ rowptr, float* __restrict__ dinv, int N) {
    __shared__ int lds[256];
    int t = threadIdx.x;
    int base = blockIdx.x * 1024 + t * 4;
    int c[4]; int s = 0;
    #pragma unroll
    for (int k = 0; k < 4; k++) {
        int i = base + k;
        if (i < N) {
            unsigned long long v = packed[i];
            c[k] = (int)(v >> 40);
            dinv[i] = rsqrtf((float)(v & ((1ULL << 40) - 1)) * (1.0f / FIXSCALE) + 1.0f);
        } else c[k] = 0;
        s += c[k];
    }
    lds[t] = s; __syncthreads();
    for (int off = 1; off < 256; off <<= 1) {
        int add = (t >= off) ? lds[t - off] : 0;
        __syncthreads();
        lds[t] += add;
        __syncthreads();
    }
    int start = bsum[blockIdx.x] + lds[t] - s;
    #pragma unroll
    for (int k = 0; k < 4; k++) {
        int i = base + k;
        if (i < N) { rowptr[i] = start; start += c[k]; }
    }
}

// fill (no atomics): edata[rowptr[d] + rank[e]] = {src, norm}
__global__ void fill2_kernel(const int* __restrict__ ei, const float* __restrict__ ew,
                             const float* __restrict__ dinv, const int* __restrict__ rowptr,
                             const int* __restrict__ rank, int2* __restrict__ edata, int E) {
    int m64 = detect_m64(ei);
    int e = blockIdx.x * blockDim.x + threadIdx.x;
    if (e < E) {
        int s = edge_val(ei, e, m64);
        int d = edge_val(ei, (long long)E + e, m64);
        float norm = dinv[s] * ew[e] * dinv[d];
        edata[rowptr[d] + rank[e]] = make_int2(s, __float_as_int(norm));
    }
}

// ---------------- W1 transpose+cast: W1T[n][k] = (f16)W1[k][n] ---------------
__global__ void trw1_kernel(const float* __restrict__ W, _Float16* __restrict__ W1T) {
    int tid = blockIdx.x * 256 + threadIdx.x;   // 64*512 = 32768 total
    int n = tid >> 9, k = tid & 511;
    W1T[tid] = (_Float16)W[k * H + n];
}

// ---------------- GEMM1 (MFMA f16): xw1[N,64] = x[N,512] @ W1 ----------------
// 128x64 tile/block, 4 waves; per wave 2 row-tiles x 4 col-tiles of 16x16,
// K-chunk 64 staged in LDS (x cast fp32->f16; W from pre-transposed W1T).
// Layouts (verified, learn_hip m89/m120): A[m=lane&15][k=quad*8+j],
// B[n=lane&15][k=quad*8+j] (from transposed LDS), C: col=lane&15,row=quad*4+reg.
#define KC 64
__global__ __launch_bounds__(256, 4) void gemm1_mfma_kernel(
        const float* __restrict__ x, const _Float16* __restrict__ W1T,
        __half* __restrict__ xwh, int N) {
    __shared__ _Float16 xsh[128][72];   // [row][k], stride 144B (16B-divisible), pad breaks 2^k
    __shared__ _Float16 wsh[64][72];    // [n][k]
    int tid  = threadIdx.x;
    int wave = tid >> 6;
    int lane = tid & 63;
    int quad = lane >> 4;
    int l16  = lane & 15;
    int row0 = blockIdx.x * 128;

    floatx4 acc[2][4];
    #pragma unroll
    for (int rt = 0; rt < 2; rt++)
        #pragma unroll
        for (int ct = 0; ct < 4; ct++) acc[rt][ct] = (floatx4){0.f, 0.f, 0.f, 0.f};

    int col4  = (tid & 15) * 4;   // x staging: k offset (16 thr/row x 4 floats = 64 k)
    int rbase = tid >> 4;         // x staging: row base
    int wn = tid >> 2;            // W staging: n (4 thr/row)
    int wk = (tid & 3) * 16;      // W staging: k offset; each thread covers 16 k (2x half8)

    for (int k0 = 0; k0 < FIN; k0 += KC) {
        #pragma unroll
        for (int it = 0; it < 8; it++) {
            int row = rbase + it * 16;
            int grow = row0 + row; if (grow >= N) grow = N - 1;
            float4 v = *(const float4*)&x[(long long)grow * FIN + k0 + col4];
            _Float16* p = &xsh[row][col4];
            p[0] = (_Float16)v.x; p[1] = (_Float16)v.y;
            p[2] = (_Float16)v.z; p[3] = (_Float16)v.w;
        }
        // FIX (r6): was one half8 per thread -> only half of wsh k-range written (NaN).
        // 4 threads/row x 16 k each = full 64-k coverage.
        *(half8*)&wsh[wn][wk]     = *(const half8*)&W1T[wn * FIN + k0 + wk];
        *(half8*)&wsh[wn][wk + 8] = *(const half8*)&W1T[wn * FIN + k0 + wk + 8];
        __syncthreads();
        #pragma unroll
        for (int kk = 0; kk < KC; kk += 32) {
            half8 a0 = *(const half8*)&xsh[wave * 32 + l16][kk + quad * 8];
            half8 a1 = *(const half8*)&xsh[wave * 32 + 16 + l16][kk + quad * 8];
            #pragma unroll
            for (int ct = 0; ct < 4; ct++) {
                half8 b = *(const half8*)&wsh[ct * 16 + l16][kk + quad * 8];
                acc[0][ct] = __builtin_amdgcn_mfma_f32_16x16x32_f16(a0, b, acc[0][ct], 0, 0, 0);
                acc[1][ct] = __builtin_amdgcn_mfma_f32_16x16x32_f16(a1, b, acc[1][ct], 0, 0, 0);
            }
        }
        __syncthreads();
    }
    #pragma unroll
    for (int rt = 0; rt < 2; rt++)
        #pragma unroll
        for (int ct = 0; ct < 4; ct++)
            #pragma unroll
            for (int r = 0; r < 4; r++) {
                int grow = row0 + wave * 32 + rt * 16 + quad * 4 + r;
                if (grow < N)
                    xwh[(long long)grow * H + ct * 16 + l16] = __float2half(acc[rt][ct][r]);
            }
}

// ---------------- agg layer 1: one wave per node, lane = feature -------------
__global__ void agg1_kernel(const int* __restrict__ rowptr, const int2* __restrict__ edata,
                            const __half* __restrict__ xwh, const float* __restrict__ dinv,
                            const float* __restrict__ b, float* __restrict__ h1, int N) {
    long long gid = (long long)blockIdx.x * blockDim.x + threadIdx.x;
    int i = (int)(gid >> 6);
    int lane = threadIdx.x & 63;
    if (i >= N) return;
    int start = rowptr[i], end = rowptr[i + 1];
    float acc = 0.f;
    int j = start;
    for (; j + 3 < end; j += 4) {
        int2 e0 = edata[j], e1 = edata[j + 1], e2 = edata[j + 2], e3 = edata[j + 3];
        float v0 = __half2float(xwh[(long long)e0.x * H + lane]);
        float v1 = __half2float(xwh[(long long)e1.x * H + lane]);
        float v2 = __half2float(xwh[(long long)e2.x * H + lane]);
        float v3 = __half2float(xwh[(long long)e3.x * H + lane]);
        acc = fmaf(v0, __int_as_float(e0.y), acc);
        acc = fmaf(v1, __int_as_float(e1.y), acc);
        acc = fmaf(v2, __int_as_float(e2.y), acc);
        acc = fmaf(v3, __int_as_float(e3.y), acc);
    }
    for (; j < end; j++) {
        int2 e0 = edata[j];
        acc = fmaf(__half2float(xwh[(long long)e0.x * H + lane]), __int_as_float(e0.y), acc);
    }
    float di = dinv[i];
    acc = fmaf(__half2float(xwh[(long long)i * H + lane]), di * di, acc);   // self-loop
    acc += b[lane];
    h1[(long long)i * H + lane] = fmaxf(acc, 0.f);           // relu
}

// ---------------- GEMM2: xw2[N,20] = h1[N,64] @ W2[64,20], fp16 out ----------
#define G2_ROWS 12
__global__ void gemm2_kernel(const float* __restrict__ h1, const float* __restrict__ W2,
                             __half* __restrict__ xw2h, int N) {
    __shared__ float hs[G2_ROWS][H + 1];
    __shared__ float ws2[H * C];
    int row0 = blockIdx.x * G2_ROWS;
    for (int t = threadIdx.x; t < H * C; t += 256) ws2[t] = W2[t];
    for (int t = threadIdx.x; t < G2_ROWS * H; t += 256) {
        int r = t >> 6, k = t & 63;
        int row = row0 + r;
        hs[r][k] = (row < N) ? h1[(long long)row * H + k] : 0.f;
    }
    __syncthreads();
    int t = threadIdx.x;
    if (t < G2_ROWS * C) {
        int r = t / C, c = t % C;
        int row = row0 + r;
        if (row < N) {
            float acc = 0.f;
            #pragma unroll
            for (int k = 0; k < H; k++) acc = fmaf(hs[r][k], ws2[k * C + c], acc);
            xw2h[(long long)row * C + c] = __float2half(acc);
        }
    }
}

// ------- agg layer 2 + self-loop + bias + softmax: 2 nodes per wave ----------
__global__ void agg2_final_kernel(const int* __restrict__ rowptr, const int2* __restrict__ edata,
                                  const __half* __restrict__ xw2h, const float* __restrict__ dinv,
                                  const float* __restrict__ b2, float* __restrict__ out, int N) {
    long long gid = (long long)blockIdx.x * blockDim.x + threadIdx.x;
    int wid = (int)(gid >> 6);
    int half = (threadIdx.x & 63) >> 5;
    int l = threadIdx.x & 31;
    int i = wid * 2 + half;
    float acc = 0.f;
    bool active = (i < N) && (l < C);
    if (active) {
        int start = rowptr[i], end = rowptr[i + 1];
        int j = start;
        for (; j + 3 < end; j += 4) {
            int2 e0 = edata[j], e1 = edata[j + 1], e2 = edata[j + 2], e3 = edata[j + 3];
            float v0 = __half2float(xw2h[(long long)e0.x * C + l]);
            float v1 = __half2float(xw2h[(long long)e1.x * C + l]);
            float v2 = __half2float(xw2h[(long long)e2.x * C + l]);
            float v3 = __half2float(xw2h[(long long)e3.x * C + l]);
            acc = fmaf(v0, __int_as_float(e0.y), acc);
            acc = fmaf(v1, __int_as_float(e1.y), acc);
            acc = fmaf(v2, __int_as_float(e2.y), acc);
            acc = fmaf(v3, __int_as_float(e3.y), acc);
        }
        for (; j < end; j++) {
            int2 e = edata[j];
            acc = fmaf(__half2float(xw2h[(long long)e.x * C + l]), __int_as_float(e.y), acc);
        }
        float di = dinv[i];
        acc = fmaf(__half2float(xw2h[(long long)i * C + l]), di * di, acc);
        acc += b2[l];
    }
    float v = active ? acc : -1e30f;
    float mx = v;
    #pragma unroll
    for (int off = 16; off >= 1; off >>= 1) mx = fmaxf(mx, __shfl_xor(mx, off, 32));
    float ex = active ? expf(v - mx) : 0.f;
    float sm = ex;
    #pragma unroll
    for (int off = 16; off >= 1; off >>= 1) sm += __shfl_xor(sm, off, 32);
    if (active) out[(long long)i * C + l] = ex / sm;
}

// ---------------- launch -----------------------------------------------------
static inline size_t align256(size_t x) { return (x + 255) & ~(size_t)255; }

extern "C" void kernel_launch(void* const* d_in, const int* in_sizes, int n_in,
                              void* d_out, int out_size, void* d_ws, size_t ws_size,
                              hipStream_t stream) {
    const float* x  = (const float*)d_in[0];
    const int*   ei = (const int*)d_in[1];
    const float* ew = (const float*)d_in[2];
    const float* W1 = (const float*)d_in[3];
    const float* b1 = (const float*)d_in[4];
    const float* W2 = (const float*)d_in[5];
    const float* b2 = (const float*)d_in[6];
    float* out = (float*)d_out;

    int N = in_sizes[0] / FIN;   // 100000
    int E = in_sizes[2];         // 3200000
    int NB = (N + 1023) / 1024;  // scan blocks (98)

    char* ws = (char*)d_ws;
    size_t off = 0;
    unsigned long long* packed = (unsigned long long*)(ws + off); off = align256(off + (size_t)N * 8);
    float*    dinv   = (float*)(ws + off);    off = align256(off + (size_t)N * 4);
    int*      bsum   = (int*)(ws + off);      off = align256(off + (size_t)NB * 4);
    int*      rowptr = (int*)(ws + off);      off = align256(off + (size_t)(N + 1) * 4);
    int2*     edata  = (int2*)(ws + off);     off = align256(off + (size_t)E * 8);
    _Float16* W1T    = (_Float16*)(ws + off); off = align256(off + (size_t)H * FIN * 2);
    __half*   xw1h   = (__half*)(ws + off);   off = align256(off + (size_t)N * H * 2);
    float*    h1     = (float*)(ws + off);    off = align256(off + (size_t)N * H * 4);
    __half*   xw2h   = (__half*)(ws + off);   off = align256(off + (size_t)N * C * 2);
    // rank overlays h1: rank is dead before agg1 writes h1 (E*4 = 12.8MB < N*H*4 = 25.6MB)
    int* rank = (int*)h1;

    hipMemsetAsync(packed, 0, (size_t)N * 8, stream);

    histrank_kernel<<<(E + 255) / 256, 256, 0, stream>>>(ei, ew, packed, rank, E);

    block_sums_kernel<<<NB, 256, 0, stream>>>(packed, bsum, N);
    scan_bsums_kernel<<<1, 256, 0, stream>>>(bsum, NB, rowptr, N, E);
    scan_local_kernel<<<NB, 256, 0, stream>>>(packed, bsum, rowptr, dinv, N);

    fill2_kernel<<<(E + 255) / 256, 256, 0, stream>>>(ei, ew, dinv, rowptr, rank, edata, E);

    trw1_kernel<<<(H * FIN) / 256, 256, 0, stream>>>(W1, W1T);
    gemm1_mfma_kernel<<<(N + 127) / 128, 256, 0, stream>>>(x, W1T, xw1h, N);

    agg1_kernel<<<(int)(((long long)N * 64 + 255) / 256), 256, 0, stream>>>(
        rowptr, edata, xw1h, dinv, b1, h1, N);

    gemm2_kernel<<<(N + G2_ROWS - 1) / G2_ROWS, 256, 0, stream>>>(h1, W2, xw2h, N);

    int waves2 = (N + 1) / 2;
    agg2_final_kernel<<<(int)(((long long)waves2 * 64 + 255) / 256), 256, 0, stream>>>(
        rowptr, edata, xw2h, dinv, b2, out, N);
}